// Round 13
// baseline (899.524 us; speedup 1.0000x reference)
//
#include <hip/hip_runtime.h>

#define TT 2048
#define BB 512
#define HH 64
#define HIST 64         // history ring length (per column)
#define HPAD 68         // floats per hist row (272 B: 16B-aligned rows)

typedef float f32x2 __attribute__((ext_vector_type(2)));
typedef float f32x4 __attribute__((ext_vector_type(4)));

#define FMA2(a, b, c) __builtin_elementwise_fma((a), (b), (c))
#define LO2(q) __builtin_shufflevector((q), (q), 0, 1)
#define HI2(q) __builtin_shufflevector((q), (q), 2, 3)

// Single wave per block, TWO batch columns per wave (shared W_hh registers).
// The two independent recurrence chains interleave in one issue stream so
// each hides the other's LDS round-trip latency. 256 blocks = 1 block/CU:
// no DS-pipe contention. No barriers anywhere (same-wave in-order DS pipe).
__global__ __launch_bounds__(64, 1) void rnn_fused(
    const float* __restrict__ x,     // [T][B]
    const float* __restrict__ h0,    // [B][H]
    const float* __restrict__ Wih,   // [H]
    const float* __restrict__ Whh,   // [H][H]
    const float* __restrict__ bih,   // [H]
    const float* __restrict__ bhh,   // [H]
    const float* __restrict__ Wlin,  // [H]
    const float* __restrict__ blin,  // [1]
    float* __restrict__ y,           // [T][B]
    float* __restrict__ hN)          // [B][H]
{
    __shared__ __align__(16) float hist[2][HIST][HPAD];  // fp32 h rings
    __shared__ float xsh[2][TT + 4];                     // x columns (+pad)
    __shared__ __align__(16) float wlin_sh[HH];

    const int b0 = 2 * blockIdx.x;      // batch columns b0, b0+1
    const int b1 = b0 + 1;
    const int h  = threadIdx.x;         // hidden index / lane, 0..63

    // ---- Prologue ----
    for (int i = h; i < TT; i += 64) {
        xsh[0][i] = x[(size_t)i * BB + b0];
        xsh[1][i] = x[(size_t)i * BB + b1];
    }
    if (h < 4) { xsh[0][TT + h] = 0.f; xsh[1][TT + h] = 0.f; }

    // Pre-scale recurrent path by 2/ln2 so tanh needs no dependent multiply:
    // acc' = (2/ln2)*(W@h + x*wih + bias); e^{2*acc} = 2^{acc'}.
    const float KSC = 2.885390081777927f;  // 2/ln2

    // Full W_hh row for my h (shared by both columns): 32 packed f32x2, scaled
    f32x2 wr[32];
    const float* wp = Whh + h * HH;
#pragma unroll
    for (int i = 0; i < 32; ++i) {
        wr[i][0] = wp[2 * i + 0] * KSC;
        wr[i][1] = wp[2 * i + 1] * KSC;
    }
    const float wihs  = Wih[h] * KSC;
    const float biass = (bih[h] + bhh[h]) * KSC;
    const float bl    = blin[0];

    wlin_sh[h] = Wlin[h];
    hist[0][HIST - 1][h] = h0[b0 * HH + h];  // slot 63 = h_0
    hist[1][HIST - 1][h] = h0[b1 * HH + h];

    float hval0 = 0.f, hval1 = 0.f;
    float xw0 = fmaf(xsh[0][0], wihs, biass);
    float xw1 = fmaf(xsh[1][0], wihs, biass);

    // ---- Recurrence ----
#pragma unroll 1
    for (int tc = 0; tc < TT; tc += HIST) {
#pragma unroll 2
        for (int ti = 0; ti < HIST; ++ti) {
            const int t  = tc + ti;
            const int rs = (ti + HIST - 1) & (HIST - 1);  // slot of h_{t-1}

            const f32x4* hp0 = reinterpret_cast<const f32x4*>(&hist[0][rs][0]);
            const f32x4* hp1 = reinterpret_cast<const f32x4*>(&hist[1][rs][0]);

            // Column 0 and column 1 dot products — independent; compiler
            // interleaves the 32 reads + 64 pk_fma across both chains.
            f32x2 c0a = {xw0, 0.f}, c0b = {0.f, 0.f}, c0c = {0.f, 0.f}, c0d = {0.f, 0.f};
            f32x2 c1a = {xw1, 0.f}, c1b = {0.f, 0.f}, c1c = {0.f, 0.f}, c1d = {0.f, 0.f};
#pragma unroll
            for (int j = 0; j < 4; ++j) {
                const f32x4 p0 = hp0[4 * j + 0];
                const f32x4 p1 = hp0[4 * j + 1];
                const f32x4 p2 = hp0[4 * j + 2];
                const f32x4 p3 = hp0[4 * j + 3];
                c0a = FMA2(LO2(p0), wr[8 * j + 0], c0a);
                c0b = FMA2(HI2(p0), wr[8 * j + 1], c0b);
                c0c = FMA2(LO2(p1), wr[8 * j + 2], c0c);
                c0d = FMA2(HI2(p1), wr[8 * j + 3], c0d);
                c0a = FMA2(LO2(p2), wr[8 * j + 4], c0a);
                c0b = FMA2(HI2(p2), wr[8 * j + 5], c0b);
                c0c = FMA2(LO2(p3), wr[8 * j + 6], c0c);
                c0d = FMA2(HI2(p3), wr[8 * j + 7], c0d);
            }
#pragma unroll
            for (int j = 0; j < 4; ++j) {
                const f32x4 p0 = hp1[4 * j + 0];
                const f32x4 p1 = hp1[4 * j + 1];
                const f32x4 p2 = hp1[4 * j + 2];
                const f32x4 p3 = hp1[4 * j + 3];
                c1a = FMA2(LO2(p0), wr[8 * j + 0], c1a);
                c1b = FMA2(HI2(p0), wr[8 * j + 1], c1b);
                c1c = FMA2(LO2(p1), wr[8 * j + 2], c1c);
                c1d = FMA2(HI2(p1), wr[8 * j + 3], c1d);
                c1a = FMA2(LO2(p2), wr[8 * j + 4], c1a);
                c1b = FMA2(HI2(p2), wr[8 * j + 5], c1b);
                c1c = FMA2(LO2(p3), wr[8 * j + 6], c1c);
                c1d = FMA2(HI2(p3), wr[8 * j + 7], c1d);
            }
            const f32x2 s20 = (c0a + c0b) + (c0c + c0d);
            const f32x2 s21 = (c1a + c1b) + (c1c + c1d);
            const float acc0 = s20[0] + s20[1];
            const float acc1 = s21[0] + s21[1];

            // tanh = 1 - 2/(2^{acc'}+1)  (weights pre-scaled; no mul before exp2)
            const float e20 = __builtin_amdgcn_exp2f(acc0);
            const float e21 = __builtin_amdgcn_exp2f(acc1);
            const float r0  = __builtin_amdgcn_rcpf(e20 + 1.0f);
            const float r1  = __builtin_amdgcn_rcpf(e21 + 1.0f);
            hval0 = fmaf(-2.0f, r0, 1.0f);
            hval1 = fmaf(-2.0f, r1, 1.0f);

            // publish h_t
            hist[0][ti][h] = hval0;
            hist[1][ti][h] = hval1;

            // x-projection for t+1 — independent, hides in latency shadow
            xw0 = fmaf(xsh[0][t + 1], wihs, biass);
            xw1 = fmaf(xsh[1][t + 1], wihs, biass);
        }

        // ---- bulk y for this chunk: lane h -> slot h, both columns ----
        {
            const f32x4* rp0 = reinterpret_cast<const f32x4*>(&hist[0][h][0]);
            const f32x4* rp1 = reinterpret_cast<const f32x4*>(&hist[1][h][0]);
            const f32x4* wl  = reinterpret_cast<const f32x4*>(&wlin_sh[0]);
            f32x2 a0 = {0.f, 0.f}, a1 = {0.f, 0.f};
#pragma unroll
            for (int i = 0; i < 16; ++i) {
                const f32x4 qw = wl[i];
                const f32x4 q0 = rp0[i];
                const f32x4 q1 = rp1[i];
                a0 = FMA2(LO2(q0), LO2(qw), a0);
                a0 = FMA2(HI2(q0), HI2(qw), a0);
                a1 = FMA2(LO2(q1), LO2(qw), a1);
                a1 = FMA2(HI2(q1), HI2(qw), a1);
            }
            y[(size_t)(tc + h) * BB + b0] = a0[0] + a0[1] + bl;
            y[(size_t)(tc + h) * BB + b1] = a1[0] + a1[1] + bl;
        }
        // same wave: next chunk's ring writes are ordered after these reads
    }

    // ---- Epilogue ----
    hN[b0 * HH + h] = hval0;
    hN[b1 * HH + h] = hval1;
}

extern "C" void kernel_launch(void* const* d_in, const int* in_sizes, int n_in,
                              void* d_out, int out_size, void* d_ws, size_t ws_size,
                              hipStream_t stream) {
    const float* x    = (const float*)d_in[0];
    const float* h0   = (const float*)d_in[1];
    const float* Wih  = (const float*)d_in[2];
    const float* Whh  = (const float*)d_in[3];
    const float* bih  = (const float*)d_in[4];
    const float* bhh  = (const float*)d_in[5];
    const float* Wlin = (const float*)d_in[6];
    const float* blin = (const float*)d_in[7];

    float* y  = (float*)d_out;            // [T*B]
    float* hN = (float*)d_out + TT * BB;  // [B*H]

    rnn_fused<<<dim3(BB / 2), dim3(64), 0, stream>>>(x, h0, Wih, Whh, bih, bhh, Wlin, blin, y, hN);
}

// Round 15
// 625.709 us; speedup vs baseline: 1.4376x; 1.4376x over previous
//
#include <hip/hip_runtime.h>

#define TT 2048
#define BB 512
#define HH 64
#define HIST 64         // y history ring length
#define HPAD 68         // floats per hist row (272 B, 16B-aligned rows)

typedef float f32x2 __attribute__((ext_vector_type(2)));
typedef float f32x4 __attribute__((ext_vector_type(4)));
typedef unsigned uint2v __attribute__((ext_vector_type(2)));

#define FMA2(a, b, c) __builtin_elementwise_fma((a), (b), (c))
#define LO2(q) __builtin_shufflevector((q), (q), 0, 1)
#define HI2(q) __builtin_shufflevector((q), (q), 2, 3)

// DPP receive: value of v from lane (lane ^ c) per ctrl pattern
#define DPP_RECV(v, ctrl) \
    __int_as_float(__builtin_amdgcn_update_dpp(0, __float_as_int(v), (ctrl), 0xF, 0xF, false))

// slot n <-> destination d = lane ^ M(n); M linear over GF(2) with
// M(1)=1, M(2)=2, M(4)=7, M(8)=15, M(16)=16, M(32)=32  (stage lane-xor consts)
__device__ __forceinline__ int Mmap(int n) {
    int m = 0;
    if (n & 1)  m ^= 1;
    if (n & 2)  m ^= 2;
    if (n & 4)  m ^= 7;
    if (n & 8)  m ^= 15;
    if (n & 16) m ^= 16;
    if (n & 32) m ^= 32;
    return m;
}

// POLARITY-INDEPENDENT partner fetch. With r = permlane16_swap(v, v) the two
// outputs are {even-rows-dup, odd-rows-dup} in SOME order; their sum equals
// v(l) + v(l^16) at every lane regardless of the builtin's return order.
// Partner = sum - own.
__device__ __forceinline__ float recv16(float v) {
#if __has_builtin(__builtin_amdgcn_permlane16_swap)
    uint2v r = __builtin_amdgcn_permlane16_swap(__float_as_uint(v), __float_as_uint(v), false, false);
    return (__uint_as_float(r[0]) + __uint_as_float(r[1])) - v;
#else
    float a = v, b = v;
    asm volatile("s_nop 1\n\tv_permlane16_swap_b32 %0, %1" : "+v"(a), "+v"(b));
    return (a + b) - v;
#endif
}
__device__ __forceinline__ float recv32(float v) {
#if __has_builtin(__builtin_amdgcn_permlane32_swap)
    uint2v r = __builtin_amdgcn_permlane32_swap(__float_as_uint(v), __float_as_uint(v), false, false);
    return (__uint_as_float(r[0]) + __uint_as_float(r[1])) - v;
#else
    float a = v, b = v;
    asm volatile("s_nop 1\n\tv_permlane32_swap_b32 %0, %1" : "+v"(a), "+v"(b));
    return (a + b) - v;
#endif
}

#define Q(n) qv[(n) >> 1][(n) & 1]

// One wave per block, one batch column per wave. The recurrence runs entirely
// in registers + cross-lane ops: no LDS h-exchange, no barriers, no DS reads
// on the critical path (R12/R13 showed the DS pipe was the floor).
__global__ __launch_bounds__(64, 1) void rnn_fused(
    const float* __restrict__ x,     // [T][B]
    const float* __restrict__ h0,    // [B][H]
    const float* __restrict__ Wih,   // [H]
    const float* __restrict__ Whh,   // [H][H]
    const float* __restrict__ bih,   // [H]
    const float* __restrict__ bhh,   // [H]
    const float* __restrict__ Wlin,  // [H]
    const float* __restrict__ blin,  // [1]
    float* __restrict__ y,           // [T][B]
    float* __restrict__ hN)          // [B][H]
{
    __shared__ float wsh[HH * HH];                    // W_hh staging for gather
    __shared__ float xsh[TT + 4];                     // x column (+pad)
    __shared__ __align__(16) float hist[HIST][HPAD];  // h ring (y only)
    __shared__ __align__(16) float wlin_sh[HH];

    const int b = blockIdx.x;   // batch column
    const int h = threadIdx.x;  // hidden index / lane

    // ---- Prologue (single wave, in-order DS pipe: no barriers) ----
    for (int i = h; i < HH * HH; i += 64) wsh[i] = Whh[i];
    for (int i = h; i < TT; i += 64)      xsh[i] = x[(size_t)i * BB + b];
    if (h < 4) xsh[TT + h] = 0.f;
    wlin_sh[h] = Wlin[h];

    const float KSC = 2.885390081777927f;  // 2/ln2 pre-scale (tanh via exp2)

    // my XOR-ordered W_hh column: wc[n] = W[(h ^ M(n))][h] * KSC
    f32x2 wc[32];
#pragma unroll
    for (int n = 0; n < 64; n += 2) {
        wc[n >> 1][0] = wsh[((h ^ Mmap(n))     << 6) | h] * KSC;
        wc[n >> 1][1] = wsh[((h ^ Mmap(n + 1)) << 6) | h] * KSC;
    }
    const float wihs  = Wih[h] * KSC;
    const float biass = (bih[h] + bhh[h]) * KSC;
    const float bl    = blin[0];

    float hval = h0[(size_t)b * HH + h];        // lane h holds h_h — stays in-lane
    float xw   = fmaf(xsh[0], wihs, biass);     // x-projection for step 0

    // ---- Recurrence: pure register/cross-lane; 1 ds_write per step (y ring) ----
#pragma unroll 1
    for (int tc = 0; tc < TT; tc += HIST) {
#pragma unroll 2
        for (int ti = 0; ti < HIST; ++ti) {
            const int t = tc + ti;

            // partials: q[n] = W[h^M(n)][h]*h_h  (xw folded into slot 0)
            const f32x2 hv2 = {hval, hval};
            f32x2 qv[32];
            {
                const f32x2 seed = {xw, 0.f};
                qv[0] = FMA2(wc[0], hv2, seed);
            }
#pragma unroll
            for (int i = 1; i < 32; ++i) qv[i] = wc[i] * hv2;

            // butterfly reduce-scatter: destination d converges to lane d
            // stage 0: lane^1 (quad_perm [1,0,3,2])
#pragma unroll
            for (int n = 0; n < 64; n += 2)  Q(n) += DPP_RECV(Q(n + 1), 0xB1);
            // stage 1: lane^2 (quad_perm [2,3,0,1])
#pragma unroll
            for (int n = 0; n < 64; n += 4)  Q(n) += DPP_RECV(Q(n + 2), 0x4E);
            // stage 2: lane^7 (row_half_mirror)
#pragma unroll
            for (int n = 0; n < 64; n += 8)  Q(n) += DPP_RECV(Q(n + 4), 0x141);
            // stage 3: lane^15 (row_mirror)
#pragma unroll
            for (int n = 0; n < 64; n += 16) Q(n) += DPP_RECV(Q(n + 8), 0x140);
            // stage 4: lane^16 (permlane16_swap, polarity-independent)
            Q(0)  += recv16(Q(16));
            Q(32) += recv16(Q(48));
            // stage 5: lane^32 (permlane32_swap, polarity-independent)
            Q(0)  += recv32(Q(32));

            const float acc = Q(0);  // full dot + xw + bias, pre-scaled by 2/ln2

            // tanh = 1 - 2/(2^{acc}+1)
            const float e2 = __builtin_amdgcn_exp2f(acc);
            const float r  = __builtin_amdgcn_rcpf(e2 + 1.0f);
            hval = fmaf(-2.0f, r, 1.0f);

            // y ring (off critical path; 2 lanes/bank = free)
            hist[ti][h] = hval;

            // next-step x projection (independent)
            xw = fmaf(xsh[t + 1], wihs, biass);
        }

        // ---- bulk y: lane h -> t = tc + h ----
        {
            const f32x4* rp = reinterpret_cast<const f32x4*>(&hist[h][0]);
            const f32x4* wl = reinterpret_cast<const f32x4*>(&wlin_sh[0]);
            f32x2 a2 = {0.f, 0.f};
#pragma unroll
            for (int i = 0; i < 16; ++i) {
                const f32x4 qq = rp[i];
                const f32x4 qw = wl[i];
                a2 = FMA2(LO2(qq), LO2(qw), a2);
                a2 = FMA2(HI2(qq), HI2(qw), a2);
            }
            y[(size_t)(tc + h) * BB + b] = a2[0] + a2[1] + bl;
        }
        // same wave: next chunk's ring writes are ordered after these reads
    }

    // ---- Epilogue ----
    hN[(size_t)b * HH + h] = hval;
}

extern "C" void kernel_launch(void* const* d_in, const int* in_sizes, int n_in,
                              void* d_out, int out_size, void* d_ws, size_t ws_size,
                              hipStream_t stream) {
    const float* x    = (const float*)d_in[0];
    const float* h0   = (const float*)d_in[1];
    const float* Wih  = (const float*)d_in[2];
    const float* Whh  = (const float*)d_in[3];
    const float* bih  = (const float*)d_in[4];
    const float* bhh  = (const float*)d_in[5];
    const float* Wlin = (const float*)d_in[6];
    const float* blin = (const float*)d_in[7];

    float* y  = (float*)d_out;            // [T*B]
    float* hN = (float*)d_out + TT * BB;  // [B*H]

    rnn_fused<<<dim3(BB), dim3(64), 0, stream>>>(x, h0, Wih, Whh, bih, bhh, Wlin, blin, y, hN);
}

// Round 16
// 381.416 us; speedup vs baseline: 2.3584x; 1.6405x over previous
//
#include <hip/hip_runtime.h>

#define TT 2048
#define BB 512
#define HH 64
#define HIST 64         // history ring length
#define HPAD 68         // floats per hist row (272 B, 16B-aligned rows)

typedef float f32x2 __attribute__((ext_vector_type(2)));
typedef float f32x4 __attribute__((ext_vector_type(4)));

#define FMA2(a, b, c) __builtin_elementwise_fma((a), (b), (c))
#define LO2(q) __builtin_shufflevector((q), (q), 0, 1)
#define HI2(q) __builtin_shufflevector((q), (q), 2, 3)

// quad DPP add: v += value from lane^1 (0xB1) or lane^2 (0x4E) within quad
#define DPP_ADD(v, ctrl) \
    ((v) + __int_as_float(__builtin_amdgcn_update_dpp(0, __float_as_int(v), (ctrl), 0xF, 0xF, false)))

// Single wave per block; K-split-4 WITHIN the wave (no barriers, no cross-wave
// exchange). Per step only 5 DS instructions: 4 ds_read_b128 (each lane's K=16
// slice, 16-lane broadcast groups) + 1 ds_write_b32 (publish into hist ring).
// R12's floor was DS-pipe throughput (16 reads/step); this cuts it 3.4x.
__global__ __launch_bounds__(64, 1) void rnn_fused(
    const float* __restrict__ x,     // [T][B]
    const float* __restrict__ h0,    // [B][H]
    const float* __restrict__ Wih,   // [H]
    const float* __restrict__ Whh,   // [H][H]
    const float* __restrict__ bih,   // [H]
    const float* __restrict__ bhh,   // [H]
    const float* __restrict__ Wlin,  // [H]
    const float* __restrict__ blin,  // [1]
    float* __restrict__ y,           // [T][B]
    float* __restrict__ hN)          // [B][H]
{
    __shared__ float wsh[HH * HH];                    // W_hh staging for gather
    __shared__ float xsh[TT + 4];                     // x column (+pad)
    __shared__ __align__(16) float hist[HIST][HPAD];  // h ring
    __shared__ __align__(16) float wlin_sh[HH];

    const int b    = blockIdx.x;    // batch column
    const int lane = threadIdx.x;   // 0..63
    const int hl   = lane >> 2;     // 0..15
    const int ks   = lane & 3;      // K-slice 0..3
    const int d    = ks * 16 + hl;  // this lane's output index

    // ---- Prologue (single wave, in-order DS pipe: no barriers) ----
    for (int i = lane; i < HH * HH; i += 64) wsh[i] = Whh[i];
    for (int i = lane; i < TT; i += 64)      xsh[i] = x[(size_t)i * BB + b];
    if (lane < 4) xsh[TT + lane] = 0.f;
    wlin_sh[lane] = Wlin[lane];

    const float KSC = 2.885390081777927f;  // 2/ln2 pre-scale (tanh via exp2)

    // weights: group g's output is g*16+hl; my K-slice cols [ks*16, ks*16+16)
    // wr[g*8+i] = {W[g*16+hl][ks*16+2i], W[g*16+hl][ks*16+2i+1]} * KSC
    f32x2 wr[32];
#pragma unroll
    for (int g = 0; g < 4; ++g) {
        const float* row = &wsh[(g * 16 + hl) * HH + ks * 16];
#pragma unroll
        for (int i = 0; i < 8; ++i) {
            wr[g * 8 + i][0] = row[2 * i + 0] * KSC;
            wr[g * 8 + i][1] = row[2 * i + 1] * KSC;
        }
    }
    const float wihs  = Wih[d] * KSC;
    const float biass = (bih[d] + bhh[d]) * KSC;
    const float bl    = blin[0];

    hist[HIST - 1][d] = h0[(size_t)b * HH + d];  // slot 63 = h_0
    float hval = 0.f;
    float xw   = fmaf(xsh[0], wihs, biass);      // x-projection for step 0

    // ---- Recurrence ----
#pragma unroll 1
    for (int tc = 0; tc < TT; tc += HIST) {
#pragma unroll 2
        for (int ti = 0; ti < HIST; ++ti) {
            const int t  = tc + ti;
            const int rs = (ti + HIST - 1) & (HIST - 1);  // slot of h_{t-1}

            // my K=16 slice of h_prev: 4 ds_read_b128, 16-lane broadcast groups
            const f32x4* hp = reinterpret_cast<const f32x4*>(&hist[rs][ks * 16]);
            const f32x4 p0 = hp[0], p1 = hp[1], p2 = hp[2], p3 = hp[3];
            const f32x2 d0 = LO2(p0), d1 = HI2(p0), d2 = LO2(p1), d3 = HI2(p1);
            const f32x2 d4 = LO2(p2), d5 = HI2(p2), d6 = LO2(p3), d7 = HI2(p3);

            // 4 output groups x K=16: 8 pk_fma each, 2 chains per group
            f32x2 g0a = {0.f, 0.f}, g0b = {0.f, 0.f};
            f32x2 g1a = {0.f, 0.f}, g1b = {0.f, 0.f};
            f32x2 g2a = {0.f, 0.f}, g2b = {0.f, 0.f};
            f32x2 g3a = {0.f, 0.f}, g3b = {0.f, 0.f};
            g0a = FMA2(d0, wr[0],  g0a); g0b = FMA2(d1, wr[1],  g0b);
            g0a = FMA2(d2, wr[2],  g0a); g0b = FMA2(d3, wr[3],  g0b);
            g0a = FMA2(d4, wr[4],  g0a); g0b = FMA2(d5, wr[5],  g0b);
            g0a = FMA2(d6, wr[6],  g0a); g0b = FMA2(d7, wr[7],  g0b);
            g1a = FMA2(d0, wr[8],  g1a); g1b = FMA2(d1, wr[9],  g1b);
            g1a = FMA2(d2, wr[10], g1a); g1b = FMA2(d3, wr[11], g1b);
            g1a = FMA2(d4, wr[12], g1a); g1b = FMA2(d5, wr[13], g1b);
            g1a = FMA2(d6, wr[14], g1a); g1b = FMA2(d7, wr[15], g1b);
            g2a = FMA2(d0, wr[16], g2a); g2b = FMA2(d1, wr[17], g2b);
            g2a = FMA2(d2, wr[18], g2a); g2b = FMA2(d3, wr[19], g2b);
            g2a = FMA2(d4, wr[20], g2a); g2b = FMA2(d5, wr[21], g2b);
            g2a = FMA2(d6, wr[22], g2a); g2b = FMA2(d7, wr[23], g2b);
            g3a = FMA2(d0, wr[24], g3a); g3b = FMA2(d1, wr[25], g3b);
            g3a = FMA2(d2, wr[26], g3a); g3b = FMA2(d3, wr[27], g3b);
            g3a = FMA2(d4, wr[28], g3a); g3b = FMA2(d5, wr[29], g3b);
            g3a = FMA2(d6, wr[30], g3a); g3b = FMA2(d7, wr[31], g3b);

            const f32x2 h0v = g0a + g0b, h1v = g1a + g1b;
            const f32x2 h2v = g2a + g2b, h3v = g3a + g3b;
            float s0 = h0v[0] + h0v[1];
            float s1 = h1v[0] + h1v[1];
            float s2 = h2v[0] + h2v[1];
            float s3 = h3v[0] + h3v[1];

            // complete each group's K=64 dot across the quad (ks dimension)
            s0 = DPP_ADD(s0, 0xB1); s0 = DPP_ADD(s0, 0x4E);
            s1 = DPP_ADD(s1, 0xB1); s1 = DPP_ADD(s1, 0x4E);
            s2 = DPP_ADD(s2, 0xB1); s2 = DPP_ADD(s2, 0x4E);
            s3 = DPP_ADD(s3, 0xB1); s3 = DPP_ADD(s3, 0x4E);

            // select my group's sum (static cndmask tree, no dynamic indexing)
            const float sA = (ks & 1) ? s1 : s0;
            const float sB = (ks & 1) ? s3 : s2;
            const float s  = (ks & 2) ? sB : sA;

            const float acc = s + xw;  // pre-scaled by 2/ln2

            // tanh = 1 - 2/(2^{acc}+1)
            const float e2 = __builtin_amdgcn_exp2f(acc);
            const float r  = __builtin_amdgcn_rcpf(e2 + 1.0f);
            hval = fmaf(-2.0f, r, 1.0f);

            // publish h_t[d] (64 distinct addrs -> 2 lanes/bank, free)
            hist[ti][d] = hval;

            // next-step x projection (independent, hides in latency shadow)
            xw = fmaf(xsh[t + 1], wihs, biass);
        }

        // ---- bulk y for this chunk: lane -> t = tc + lane ----
        {
            const f32x4* rp = reinterpret_cast<const f32x4*>(&hist[lane][0]);
            const f32x4* wl = reinterpret_cast<const f32x4*>(&wlin_sh[0]);
            f32x2 a2 = {0.f, 0.f};
#pragma unroll
            for (int i = 0; i < 16; ++i) {
                const f32x4 qq = rp[i];
                const f32x4 qw = wl[i];
                a2 = FMA2(LO2(qq), LO2(qw), a2);
                a2 = FMA2(HI2(qq), HI2(qw), a2);
            }
            y[(size_t)(tc + lane) * BB + b] = a2[0] + a2[1] + bl;
        }
        // same wave: next chunk's ring writes are ordered after these reads
    }

    // ---- Epilogue ----
    hN[(size_t)b * HH + d] = hval;
}

extern "C" void kernel_launch(void* const* d_in, const int* in_sizes, int n_in,
                              void* d_out, int out_size, void* d_ws, size_t ws_size,
                              hipStream_t stream) {
    const float* x    = (const float*)d_in[0];
    const float* h0   = (const float*)d_in[1];
    const float* Wih  = (const float*)d_in[2];
    const float* Whh  = (const float*)d_in[3];
    const float* bih  = (const float*)d_in[4];
    const float* bhh  = (const float*)d_in[5];
    const float* Wlin = (const float*)d_in[6];
    const float* blin = (const float*)d_in[7];

    float* y  = (float*)d_out;            // [T*B]
    float* hN = (float*)d_out + TT * BB;  // [B*H]

    rnn_fused<<<dim3(BB), dim3(64), 0, stream>>>(x, h0, Wih, Whh, bih, bhh, Wlin, blin, y, hN);
}